// Round 2
// baseline (272.992 us; speedup 1.0000x reference)
//
#include <hip/hip_runtime.h>
#include <hip/hip_bf16.h>

// Problem: B=16, C=512, H=W=32 (N=1024), 32 groups (16 ch/group).
// Wire dtype: fp32 (per reference); internal GEMM dtype: bf16 (threshold is
// 2% of ref absmax = 1.29e-2, ample for bf16 MFMA).
// Pipeline:
//   1. gn_stats:   per (b,g) mean/var -> per (b,c) scale/shift (fp32, ws)
//   2. projw_k:    projwI = bf16(proj_weight + I)  (residual fold: ref adds o)
//   3. xn_t_k:     xn_t[b][n][c] = bf16(x*scale+shift)   (LDS transpose)
//   4. gemm_qkv:   D[n][o] = xn_t . qkv_w^T + bias; q (*C^-0.5),k -> qk[b][n][0..1024);
//                  v -> v[b][c][m]
//   5. gemm_s:     S[b][n][m] = q_t . k_t^T   (bf16)
//   6. softmax_k:  rowwise softmax in place (wave per row)
//   7. gemm_o:     ot[b][n][c] = P . v^T      (ot aliases dead qk)
//   8. gemm_proj:  out[b][o][n] = projwI . ot^T + proj_bias (fp32 out)

typedef __attribute__((ext_vector_type(8))) short bf16x8;   // 8 bf16 = 4 VGPRs
typedef __attribute__((ext_vector_type(4))) float f32x4;

__device__ __forceinline__ float b2f(ushort u) {
  unsigned int v = ((unsigned int)u) << 16;
  float f; __builtin_memcpy(&f, &v, 4); return f;
}
__device__ __forceinline__ ushort f2b(float f) {
  __hip_bfloat16 h = __float2bfloat16(f);
  ushort u; __builtin_memcpy(&u, &h, 2); return u;
}

// ---------------- GroupNorm stats -> per-(b,c) scale/shift ----------------
__global__ __launch_bounds__(256) void gn_stats_k(
    const float* __restrict__ x, const float* __restrict__ gw,
    const float* __restrict__ gb, float* __restrict__ scale,
    float* __restrict__ shift) {
  int g = blockIdx.x, b = blockIdx.y;
  const float* xp = x + ((size_t)b * 512 + g * 16) * 1024;  // 16384 contiguous
  float s = 0.f, ss = 0.f;
  for (int i = threadIdx.x; i < 4096; i += 256) {  // 4096 float4 chunks
    float4 u = ((const float4*)xp)[i];
    s += u.x + u.y + u.z + u.w;
    ss += u.x * u.x + u.y * u.y + u.z * u.z + u.w * u.w;
  }
#pragma unroll
  for (int off = 32; off >= 1; off >>= 1) {
    s += __shfl_xor(s, off); ss += __shfl_xor(ss, off);
  }
  __shared__ float sb[4], ssb[4];
  int w = threadIdx.x >> 6;
  if ((threadIdx.x & 63) == 0) { sb[w] = s; ssb[w] = ss; }
  __syncthreads();
  float st = sb[0] + sb[1] + sb[2] + sb[3];
  float sst = ssb[0] + ssb[1] + ssb[2] + ssb[3];
  float mean = st * (1.f / 16384.f);
  float var = sst * (1.f / 16384.f) - mean * mean;
  float rstd = rsqrtf(var + 1e-5f);
  if (threadIdx.x < 16) {
    int c = g * 16 + threadIdx.x;
    float wc = gw[c];
    scale[b * 512 + c] = rstd * wc;
    shift[b * 512 + c] = gb[c] - mean * rstd * wc;
  }
}

// ---------------- bf16(proj_weight + I) (residual fold) ----------------
__global__ __launch_bounds__(256) void projw_k(const float* __restrict__ pw,
                                               ushort* __restrict__ dst) {
  int i = blockIdx.x * 256 + threadIdx.x;  // 262144 total
  int r = i >> 9, c = i & 511;
  dst[i] = f2b(pw[i] + (r == c ? 1.f : 0.f));
}

// ---------------- normalize + transpose: xn_t[b][n][c] (bf16) ----------------
__global__ __launch_bounds__(256) void xn_t_k(
    const float* __restrict__ x, const float* __restrict__ scale,
    const float* __restrict__ shift, ushort* __restrict__ xt) {
  int b = blockIdx.z, c0 = blockIdx.y * 64, n0 = blockIdx.x * 64;
  __shared__ ushort tile[64][65];
  const float* xp = x + ((size_t)b * 512 + c0) * 1024 + n0;
  int t = threadIdx.x;
  int nq = t & 15, cr = t >> 4;
#pragma unroll
  for (int p = 0; p < 4; ++p) {
    int c = cr + p * 16;
    float4 v = *(const float4*)(xp + (size_t)c * 1024 + nq * 4);
    float sc = scale[b * 512 + c0 + c], sh = shift[b * 512 + c0 + c];
    tile[c][nq * 4 + 0] = f2b(v.x * sc + sh);
    tile[c][nq * 4 + 1] = f2b(v.y * sc + sh);
    tile[c][nq * 4 + 2] = f2b(v.z * sc + sh);
    tile[c][nq * 4 + 3] = f2b(v.w * sc + sh);
  }
  __syncthreads();
  ushort* op = xt + ((size_t)b * 1024 + n0) * 512 + c0;
  int cq = t & 15, nr = t >> 4;
#pragma unroll
  for (int p = 0; p < 4; ++p) {
    int n = nr + p * 16;
    ushort4 u;
    u.x = tile[cq * 4 + 0][n]; u.y = tile[cq * 4 + 1][n];
    u.z = tile[cq * 4 + 2][n]; u.w = tile[cq * 4 + 3][n];
    *(ushort4*)(op + (size_t)n * 512 + cq * 4) = u;
  }
}

// ---------------- shared 128x128 GEMM core: C = A[M][K] . B[N][K]^T ----------
// 256 threads = 4 waves in 2x2; each wave 64x64 via 4x4 mfma_f32_16x16x32_bf16.
// A-frag: m=lane&15, k=(lane>>4)*8+j ; B-frag: n=lane&15, same k (doc-verified).
__device__ __forceinline__ void gemm128(const ushort* __restrict__ Ag, int lda,
                                        const ushort* __restrict__ Bg, int ldb,
                                        int K, f32x4 (&acc)[4][4], ushort* As,
                                        ushort* Bs) {
  const int t = threadIdx.x;
  const int lane = t & 63, w = t >> 6;
  const int wm = (w >> 1) * 64, wn = (w & 1) * 64;
  const int fr = lane & 15;
  const int fk = (lane >> 4) * 8;
  for (int k0 = 0; k0 < K; k0 += 32) {
    // stage 128x32 bf16 tiles (8KB each): 16B vector loads, 16B LDS stores
#pragma unroll
    for (int ph = 0; ph < 2; ++ph) {
      int c = t + ph * 256;
      int r = c >> 2, kc = (c & 3) * 8;
      *(uint4*)(As + c * 8) = *(const uint4*)(Ag + (size_t)r * lda + k0 + kc);
      *(uint4*)(Bs + c * 8) = *(const uint4*)(Bg + (size_t)r * ldb + k0 + kc);
    }
    __syncthreads();
    bf16x8 af[4], bfr[4];
#pragma unroll
    for (int i = 0; i < 4; ++i)
      af[i] = *(const bf16x8*)(As + (wm + i * 16 + fr) * 32 + fk);
#pragma unroll
    for (int j = 0; j < 4; ++j)
      bfr[j] = *(const bf16x8*)(Bs + (wn + j * 16 + fr) * 32 + fk);
#pragma unroll
    for (int i = 0; i < 4; ++i)
#pragma unroll
      for (int j = 0; j < 4; ++j)
        acc[i][j] = __builtin_amdgcn_mfma_f32_16x16x32_bf16(af[i], bfr[j],
                                                            acc[i][j], 0, 0, 0);
    __syncthreads();
  }
}

#define GEMM_PROLOGUE()                                        \
  __shared__ ushort As[4096], Bs[4096];                        \
  f32x4 acc[4][4];                                             \
  { f32x4 z = {0.f, 0.f, 0.f, 0.f};                            \
    _Pragma("unroll") for (int i = 0; i < 4; ++i)              \
      _Pragma("unroll") for (int j = 0; j < 4; ++j) acc[i][j] = z; }

#define EPILOGUE_IDX()                                         \
  int lane = threadIdx.x & 63, w = threadIdx.x >> 6;           \
  int wm = (w >> 1) * 64, wn = (w & 1) * 64;                   \
  int ml = (lane >> 4) * 4, nl = lane & 15;

// ---------------- QKV GEMM: D[n][o] ----------------
__global__ __launch_bounds__(256) void gemm_qkv_k(
    const ushort* __restrict__ xt, const ushort* __restrict__ wqkv,
    const float* __restrict__ bias, ushort* __restrict__ qk,
    ushort* __restrict__ v) {
  int b = blockIdx.z;
  int m0 = blockIdx.x * 128;  // n-position
  int n0 = blockIdx.y * 128;  // output channel (0..1536)
  GEMM_PROLOGUE();
  const ushort* Ag = xt + ((size_t)b * 1024 + m0) * 512;
  const ushort* Bg = wqkv + (size_t)n0 * 512;
  gemm128(Ag, 512, Bg, 512, 512, acc, As, Bs);
  EPILOGUE_IDX();
  const float qscale = 0.044194173824159216f;  // 512^-0.5
#pragma unroll
  for (int i = 0; i < 4; ++i)
#pragma unroll
    for (int j = 0; j < 4; ++j) {
      int gn = n0 + wn + j * 16 + nl;  // o-channel
      float bs = bias[gn];
#pragma unroll
      for (int r = 0; r < 4; ++r) {
        int gm = m0 + wm + i * 16 + ml + r;  // n-position
        float val = acc[i][j][r] + bs;
        if (gn < 1024) {  // block-uniform branch (128-wide o-tiles)
          if (gn < 512) val *= qscale;
          qk[((size_t)b * 1024 + gm) * 1024 + gn] = f2b(val);
        } else {
          v[((size_t)b * 512 + (gn - 1024)) * 1024 + gm] = f2b(val);
        }
      }
    }
}

// ---------------- bf16 qkv_weight staging is free: wqkv arrives fp32 --------
__global__ __launch_bounds__(256) void cvt_w_k(const float* __restrict__ src,
                                               ushort* __restrict__ dst,
                                               int n) {
  int i = blockIdx.x * 256 + threadIdx.x;
  if (i < n) dst[i] = f2b(src[i]);
}

// ---------------- S GEMM: S[n][m] = q_t . k_t^T ----------------
__global__ __launch_bounds__(256) void gemm_s_k(const ushort* __restrict__ qk,
                                                ushort* __restrict__ S) {
  int b = blockIdx.z;
  int m0 = blockIdx.x * 128, n0 = blockIdx.y * 128;
  GEMM_PROLOGUE();
  const ushort* Ag = qk + ((size_t)b * 1024 + m0) * 1024;        // q cols 0..512
  const ushort* Bg = qk + ((size_t)b * 1024 + n0) * 1024 + 512;  // k cols 512..1024
  gemm128(Ag, 1024, Bg, 1024, 512, acc, As, Bs);
  EPILOGUE_IDX();
#pragma unroll
  for (int i = 0; i < 4; ++i)
#pragma unroll
    for (int j = 0; j < 4; ++j)
#pragma unroll
      for (int r = 0; r < 4; ++r) {
        int gm = m0 + wm + i * 16 + ml + r, gn = n0 + wn + j * 16 + nl;
        S[((size_t)b * 1024 + gm) * 1024 + gn] = f2b(acc[i][j][r]);
      }
}

// ---------------- rowwise softmax in place (wave per row, bf16) ----------------
__global__ __launch_bounds__(256) void softmax_k(ushort* __restrict__ S) {
  int row = blockIdx.x * 4 + (threadIdx.x >> 6);
  int lane = threadIdx.x & 63;
  ushort* p = S + (size_t)row * 1024 + lane * 16;
  uint4 u0 = *(uint4*)p, u1 = *(uint4*)(p + 8);
  float v[16];
  const ushort* e0 = (const ushort*)&u0;
  const ushort* e1 = (const ushort*)&u1;
#pragma unroll
  for (int j = 0; j < 8; ++j) { v[j] = b2f(e0[j]); v[8 + j] = b2f(e1[j]); }
  float m = v[0];
#pragma unroll
  for (int j = 1; j < 16; ++j) m = fmaxf(m, v[j]);
#pragma unroll
  for (int off = 32; off >= 1; off >>= 1) m = fmaxf(m, __shfl_xor(m, off));
  float s = 0.f;
#pragma unroll
  for (int j = 0; j < 16; ++j) { v[j] = __expf(v[j] - m); s += v[j]; }
#pragma unroll
  for (int off = 32; off >= 1; off >>= 1) s += __shfl_xor(s, off);
  float inv = 1.f / s;
  uint4 r4[2];
  ushort* r = (ushort*)r4;
#pragma unroll
  for (int j = 0; j < 16; ++j) r[j] = f2b(v[j] * inv);
  *(uint4*)p = r4[0];
  *(uint4*)(p + 8) = r4[1];
}

// ---------------- O GEMM: ot[n][c] = P . v^T ----------------
__global__ __launch_bounds__(256) void gemm_o_k(const ushort* __restrict__ S,
                                                const ushort* __restrict__ v,
                                                ushort* __restrict__ ot) {
  int b = blockIdx.z;
  int m0 = blockIdx.x * 128;  // n-position
  int n0 = blockIdx.y * 128;  // channel (0..512)
  GEMM_PROLOGUE();
  const ushort* Ag = S + ((size_t)b * 1024 + m0) * 1024;
  const ushort* Bg = v + ((size_t)b * 512 + n0) * 1024;
  gemm128(Ag, 1024, Bg, 1024, 1024, acc, As, Bs);
  EPILOGUE_IDX();
#pragma unroll
  for (int i = 0; i < 4; ++i)
#pragma unroll
    for (int j = 0; j < 4; ++j)
#pragma unroll
      for (int r = 0; r < 4; ++r) {
        int gm = m0 + wm + i * 16 + ml + r, gn = n0 + wn + j * 16 + nl;
        ot[((size_t)b * 1024 + gm) * 512 + gn] = f2b(acc[i][j][r]);
      }
}

// ---------------- proj GEMM: out[o][n] = (Wp+I) . ot^T + bias (fp32 out) ----
__global__ __launch_bounds__(256) void gemm_proj_k(
    const ushort* __restrict__ pwI, const ushort* __restrict__ ot,
    const float* __restrict__ pb, float* __restrict__ out) {
  int b = blockIdx.z;
  int m0 = blockIdx.x * 128;  // o-channel (0..512)
  int n0 = blockIdx.y * 128;  // n-position
  GEMM_PROLOGUE();
  const ushort* Ag = pwI + (size_t)m0 * 512;
  const ushort* Bg = ot + ((size_t)b * 1024 + n0) * 512;
  gemm128(Ag, 512, Bg, 512, 512, acc, As, Bs);
  EPILOGUE_IDX();
#pragma unroll
  for (int i = 0; i < 4; ++i)
#pragma unroll
    for (int j = 0; j < 4; ++j)
#pragma unroll
      for (int r = 0; r < 4; ++r) {
        int gm = m0 + wm + i * 16 + ml + r;  // o-channel
        int gn = n0 + wn + j * 16 + nl;      // n-position
        out[((size_t)b * 512 + gm) * 1024 + gn] = acc[i][j][r] + pb[gm];
      }
}

extern "C" void kernel_launch(void* const* d_in, const int* in_sizes, int n_in,
                              void* d_out, int out_size, void* d_ws,
                              size_t ws_size, hipStream_t stream) {
  const float* x = (const float*)d_in[0];
  const float* gw = (const float*)d_in[1];
  const float* gb = (const float*)d_in[2];
  const float* wqkv_f = (const float*)d_in[3];
  const float* bqkv = (const float*)d_in[4];
  const float* pw = (const float*)d_in[5];
  const float* pb = (const float*)d_in[6];
  float* out = (float*)d_out;

  // Workspace layout (84.5 MB peak, region reuse):
  //   0        scale (32KB)
  //   32768    shift (32KB)
  //   65536    pwI bf16 (512KB)
  //   589824   wqkv bf16 (1.5MB)  [1536*512*2]
  //   2162688  R1 (32MB): xt[b][n][c] bf16 (first 16MB); later S[b][n][m]
  //   35717120 R2 (32MB): qk[b][n][0..1024) bf16; later ot[b][n][c] (16MB)
  //   69271552 R3 (16MB): v[b][c][m] bf16
  char* ws = (char*)d_ws;
  float* scale = (float*)(ws + 0);
  float* shift = (float*)(ws + 32768);
  ushort* pwI = (ushort*)(ws + 65536);
  ushort* wqkv = (ushort*)(ws + 589824);
  ushort* xt = (ushort*)(ws + 2162688);
  ushort* S = xt;                       // S overwrites dead xt region
  ushort* qk = (ushort*)(ws + 35717120);
  ushort* ot = qk;                      // ot overwrites dead qk region
  ushort* v = (ushort*)(ws + 69271552);

  gn_stats_k<<<dim3(32, 16), 256, 0, stream>>>(x, gw, gb, scale, shift);
  projw_k<<<dim3(1024), 256, 0, stream>>>(pw, pwI);
  cvt_w_k<<<dim3(3072), 256, 0, stream>>>(wqkv_f, wqkv, 1536 * 512);
  xn_t_k<<<dim3(16, 8, 16), 256, 0, stream>>>(x, scale, shift, xt);
  gemm_qkv_k<<<dim3(8, 12, 16), 256, 0, stream>>>(xt, wqkv, bqkv, qk, v);
  gemm_s_k<<<dim3(8, 8, 16), 256, 0, stream>>>(qk, S);
  softmax_k<<<dim3(4096), 256, 0, stream>>>(S);
  gemm_o_k<<<dim3(8, 4, 16), 256, 0, stream>>>(S, v, ot);
  gemm_proj_k<<<dim3(4, 8, 16), 256, 0, stream>>>(pwI, ot, pb, out);
}

// Round 3
// 267.376 us; speedup vs baseline: 1.0210x; 1.0210x over previous
//
#include <hip/hip_runtime.h>
#include <hip/hip_bf16.h>

// Problem: B=16, C=512, H=W=32 (N=1024), 32 groups (16 ch/group).
// Wire dtype: fp32; internal GEMM dtype: bf16.
// R2->R3 change: gemm128 staging uses __builtin_amdgcn_global_load_lds
// (width=16) instead of VGPR round-trip (doc ladder m93->m97 = 1.69x).

typedef __attribute__((ext_vector_type(8))) short bf16x8;   // 8 bf16 = 4 VGPRs
typedef __attribute__((ext_vector_type(4))) float f32x4;

__device__ __forceinline__ float b2f(ushort u) {
  unsigned int v = ((unsigned int)u) << 16;
  float f; __builtin_memcpy(&f, &v, 4); return f;
}
__device__ __forceinline__ ushort f2b(float f) {
  __hip_bfloat16 h = __float2bfloat16(f);
  ushort u; __builtin_memcpy(&u, &h, 2); return u;
}

// async global->LDS, 16B per lane. LDS dest must equal wave-uniform base +
// lane*16 (m104/m108 constraint) — our staging index c = ph*256 + w*64 + lane
// satisfies this. Casts via uintptr_t (CK idiom): global flat==as(1); LDS flat
// low 32 bits == as(3) offset.
__device__ __forceinline__ void gld_lds16(const void* g, void* l) {
  auto gp = (const __attribute__((address_space(1))) void*)(uintptr_t)(g);
  auto lp = (__attribute__((address_space(3))) void*)(uintptr_t)(l);
  __builtin_amdgcn_global_load_lds(gp, lp, 16, 0, 0);
}

// ---------------- GroupNorm stats -> per-(b,c) scale/shift ----------------
__global__ __launch_bounds__(256) void gn_stats_k(
    const float* __restrict__ x, const float* __restrict__ gw,
    const float* __restrict__ gb, float* __restrict__ scale,
    float* __restrict__ shift) {
  int g = blockIdx.x, b = blockIdx.y;
  const float* xp = x + ((size_t)b * 512 + g * 16) * 1024;  // 16384 contiguous
  float s = 0.f, ss = 0.f;
  for (int i = threadIdx.x; i < 4096; i += 256) {  // 4096 float4 chunks
    float4 u = ((const float4*)xp)[i];
    s += u.x + u.y + u.z + u.w;
    ss += u.x * u.x + u.y * u.y + u.z * u.z + u.w * u.w;
  }
#pragma unroll
  for (int off = 32; off >= 1; off >>= 1) {
    s += __shfl_xor(s, off); ss += __shfl_xor(ss, off);
  }
  __shared__ float sb[4], ssb[4];
  int w = threadIdx.x >> 6;
  if ((threadIdx.x & 63) == 0) { sb[w] = s; ssb[w] = ss; }
  __syncthreads();
  float st = sb[0] + sb[1] + sb[2] + sb[3];
  float sst = ssb[0] + ssb[1] + ssb[2] + ssb[3];
  float mean = st * (1.f / 16384.f);
  float var = sst * (1.f / 16384.f) - mean * mean;
  float rstd = rsqrtf(var + 1e-5f);
  if (threadIdx.x < 16) {
    int c = g * 16 + threadIdx.x;
    float wc = gw[c];
    scale[b * 512 + c] = rstd * wc;
    shift[b * 512 + c] = gb[c] - mean * rstd * wc;
  }
}

// ---------------- bf16(proj_weight + I) (residual fold) ----------------
__global__ __launch_bounds__(256) void projw_k(const float* __restrict__ pw,
                                               ushort* __restrict__ dst) {
  int i = blockIdx.x * 256 + threadIdx.x;  // 262144 total
  int r = i >> 9, c = i & 511;
  dst[i] = f2b(pw[i] + (r == c ? 1.f : 0.f));
}

// ---------------- normalize + transpose: xn_t[b][n][c] (bf16) ----------------
__global__ __launch_bounds__(256) void xn_t_k(
    const float* __restrict__ x, const float* __restrict__ scale,
    const float* __restrict__ shift, ushort* __restrict__ xt) {
  int b = blockIdx.z, c0 = blockIdx.y * 64, n0 = blockIdx.x * 64;
  __shared__ ushort tile[64][65];
  const float* xp = x + ((size_t)b * 512 + c0) * 1024 + n0;
  int t = threadIdx.x;
  int nq = t & 15, cr = t >> 4;
#pragma unroll
  for (int p = 0; p < 4; ++p) {
    int c = cr + p * 16;
    float4 v = *(const float4*)(xp + (size_t)c * 1024 + nq * 4);
    float sc = scale[b * 512 + c0 + c], sh = shift[b * 512 + c0 + c];
    tile[c][nq * 4 + 0] = f2b(v.x * sc + sh);
    tile[c][nq * 4 + 1] = f2b(v.y * sc + sh);
    tile[c][nq * 4 + 2] = f2b(v.z * sc + sh);
    tile[c][nq * 4 + 3] = f2b(v.w * sc + sh);
  }
  __syncthreads();
  ushort* op = xt + ((size_t)b * 1024 + n0) * 512 + c0;
  int cq = t & 15, nr = t >> 4;
#pragma unroll
  for (int p = 0; p < 4; ++p) {
    int n = nr + p * 16;
    ushort4 u;
    u.x = tile[cq * 4 + 0][n]; u.y = tile[cq * 4 + 1][n];
    u.z = tile[cq * 4 + 2][n]; u.w = tile[cq * 4 + 3][n];
    *(ushort4*)(op + (size_t)n * 512 + cq * 4) = u;
  }
}

// ---------------- shared 128x128 GEMM core: C = A[M][K] . B[N][K]^T ----------
// 256 threads = 4 waves in 2x2; each wave 64x64 via 4x4 mfma_f32_16x16x32_bf16.
// A-frag: m=lane&15, k=(lane>>4)*8+j ; B-frag: n=lane&15, same k (doc-verified).
__device__ __forceinline__ void gemm128(const ushort* __restrict__ Ag, int lda,
                                        const ushort* __restrict__ Bg, int ldb,
                                        int K, f32x4 (&acc)[4][4], ushort* As,
                                        ushort* Bs) {
  const int t = threadIdx.x;
  const int lane = t & 63, w = t >> 6;
  const int wm = (w >> 1) * 64, wn = (w & 1) * 64;
  const int fr = lane & 15;
  const int fk = (lane >> 4) * 8;
  for (int k0 = 0; k0 < K; k0 += 32) {
    // stage 128x32 bf16 tiles (8KB each) via async global->LDS dwordx4.
    // chunk c = ph*256 + t = (ph*4 + w)*64 + lane; LDS offset c*16 bytes
    // = wave-uniform base + lane*16. Global src: row r=c>>2, kchunk (c&3)*8.
#pragma unroll
    for (int ph = 0; ph < 2; ++ph) {
      int c = ph * 256 + t;
      int r = c >> 2, kc = (c & 3) * 8;
      gld_lds16(Ag + (size_t)r * lda + k0 + kc, As + c * 8);
      gld_lds16(Bg + (size_t)r * ldb + k0 + kc, Bs + c * 8);
    }
    __syncthreads();
    bf16x8 af[4], bfr[4];
#pragma unroll
    for (int i = 0; i < 4; ++i)
      af[i] = *(const bf16x8*)(As + (wm + i * 16 + fr) * 32 + fk);
#pragma unroll
    for (int j = 0; j < 4; ++j)
      bfr[j] = *(const bf16x8*)(Bs + (wn + j * 16 + fr) * 32 + fk);
#pragma unroll
    for (int i = 0; i < 4; ++i)
#pragma unroll
      for (int j = 0; j < 4; ++j)
        acc[i][j] = __builtin_amdgcn_mfma_f32_16x16x32_bf16(af[i], bfr[j],
                                                            acc[i][j], 0, 0, 0);
    __syncthreads();
  }
}

#define GEMM_PROLOGUE()                                        \
  __shared__ ushort As[4096], Bs[4096];                        \
  f32x4 acc[4][4];                                             \
  { f32x4 z = {0.f, 0.f, 0.f, 0.f};                            \
    _Pragma("unroll") for (int i = 0; i < 4; ++i)              \
      _Pragma("unroll") for (int j = 0; j < 4; ++j) acc[i][j] = z; }

#define EPILOGUE_IDX()                                         \
  int lane = threadIdx.x & 63, w = threadIdx.x >> 6;           \
  int wm = (w >> 1) * 64, wn = (w & 1) * 64;                   \
  int ml = (lane >> 4) * 4, nl = lane & 15;

// ---------------- QKV GEMM: D[n][o] ----------------
__global__ __launch_bounds__(256) void gemm_qkv_k(
    const ushort* __restrict__ xt, const ushort* __restrict__ wqkv,
    const float* __restrict__ bias, ushort* __restrict__ qk,
    ushort* __restrict__ v) {
  int b = blockIdx.z;
  int m0 = blockIdx.x * 128;  // n-position
  int n0 = blockIdx.y * 128;  // output channel (0..1536)
  GEMM_PROLOGUE();
  const ushort* Ag = xt + ((size_t)b * 1024 + m0) * 512;
  const ushort* Bg = wqkv + (size_t)n0 * 512;
  gemm128(Ag, 512, Bg, 512, 512, acc, As, Bs);
  EPILOGUE_IDX();
  const float qscale = 0.044194173824159216f;  // 512^-0.5
#pragma unroll
  for (int i = 0; i < 4; ++i)
#pragma unroll
    for (int j = 0; j < 4; ++j) {
      int gn = n0 + wn + j * 16 + nl;  // o-channel
      float bs = bias[gn];
#pragma unroll
      for (int r = 0; r < 4; ++r) {
        int gm = m0 + wm + i * 16 + ml + r;  // n-position
        float val = acc[i][j][r] + bs;
        if (gn < 1024) {  // block-uniform branch (128-wide o-tiles)
          if (gn < 512) val *= qscale;
          qk[((size_t)b * 1024 + gm) * 1024 + gn] = f2b(val);
        } else {
          v[((size_t)b * 512 + (gn - 1024)) * 1024 + gm] = f2b(val);
        }
      }
    }
}

// ---------------- bf16 qkv_weight staging: wqkv arrives fp32 --------
__global__ __launch_bounds__(256) void cvt_w_k(const float* __restrict__ src,
                                               ushort* __restrict__ dst,
                                               int n) {
  int i = blockIdx.x * 256 + threadIdx.x;
  if (i < n) dst[i] = f2b(src[i]);
}

// ---------------- S GEMM: S[n][m] = q_t . k_t^T ----------------
__global__ __launch_bounds__(256) void gemm_s_k(const ushort* __restrict__ qk,
                                                ushort* __restrict__ S) {
  int b = blockIdx.z;
  int m0 = blockIdx.x * 128, n0 = blockIdx.y * 128;
  GEMM_PROLOGUE();
  const ushort* Ag = qk + ((size_t)b * 1024 + m0) * 1024;        // q cols 0..512
  const ushort* Bg = qk + ((size_t)b * 1024 + n0) * 1024 + 512;  // k cols 512..1024
  gemm128(Ag, 1024, Bg, 1024, 512, acc, As, Bs);
  EPILOGUE_IDX();
#pragma unroll
  for (int i = 0; i < 4; ++i)
#pragma unroll
    for (int j = 0; j < 4; ++j)
#pragma unroll
      for (int r = 0; r < 4; ++r) {
        int gm = m0 + wm + i * 16 + ml + r, gn = n0 + wn + j * 16 + nl;
        S[((size_t)b * 1024 + gm) * 1024 + gn] = f2b(acc[i][j][r]);
      }
}

// ---------------- rowwise softmax in place (wave per row, bf16) ----------------
__global__ __launch_bounds__(256) void softmax_k(ushort* __restrict__ S) {
  int row = blockIdx.x * 4 + (threadIdx.x >> 6);
  int lane = threadIdx.x & 63;
  ushort* p = S + (size_t)row * 1024 + lane * 16;
  uint4 u0 = *(uint4*)p, u1 = *(uint4*)(p + 8);
  float v[16];
  const ushort* e0 = (const ushort*)&u0;
  const ushort* e1 = (const ushort*)&u1;
#pragma unroll
  for (int j = 0; j < 8; ++j) { v[j] = b2f(e0[j]); v[8 + j] = b2f(e1[j]); }
  float m = v[0];
#pragma unroll
  for (int j = 1; j < 16; ++j) m = fmaxf(m, v[j]);
#pragma unroll
  for (int off = 32; off >= 1; off >>= 1) m = fmaxf(m, __shfl_xor(m, off));
  float s = 0.f;
#pragma unroll
  for (int j = 0; j < 16; ++j) { v[j] = __expf(v[j] - m); s += v[j]; }
#pragma unroll
  for (int off = 32; off >= 1; off >>= 1) s += __shfl_xor(s, off);
  float inv = 1.f / s;
  uint4 r4[2];
  ushort* r = (ushort*)r4;
#pragma unroll
  for (int j = 0; j < 16; ++j) r[j] = f2b(v[j] * inv);
  *(uint4*)p = r4[0];
  *(uint4*)(p + 8) = r4[1];
}

// ---------------- O GEMM: ot[n][c] = P . v^T ----------------
__global__ __launch_bounds__(256) void gemm_o_k(const ushort* __restrict__ S,
                                                const ushort* __restrict__ v,
                                                ushort* __restrict__ ot) {
  int b = blockIdx.z;
  int m0 = blockIdx.x * 128;  // n-position
  int n0 = blockIdx.y * 128;  // channel (0..512)
  GEMM_PROLOGUE();
  const ushort* Ag = S + ((size_t)b * 1024 + m0) * 1024;
  const ushort* Bg = v + ((size_t)b * 512 + n0) * 1024;
  gemm128(Ag, 1024, Bg, 1024, 1024, acc, As, Bs);
  EPILOGUE_IDX();
#pragma unroll
  for (int i = 0; i < 4; ++i)
#pragma unroll
    for (int j = 0; j < 4; ++j)
#pragma unroll
      for (int r = 0; r < 4; ++r) {
        int gm = m0 + wm + i * 16 + ml + r, gn = n0 + wn + j * 16 + nl;
        ot[((size_t)b * 1024 + gm) * 512 + gn] = f2b(acc[i][j][r]);
      }
}

// ---------------- proj GEMM: out[o][n] = (Wp+I) . ot^T + bias (fp32 out) ----
__global__ __launch_bounds__(256) void gemm_proj_k(
    const ushort* __restrict__ pwI, const ushort* __restrict__ ot,
    const float* __restrict__ pb, float* __restrict__ out) {
  int b = blockIdx.z;
  int m0 = blockIdx.x * 128;  // o-channel (0..512)
  int n0 = blockIdx.y * 128;  // n-position
  GEMM_PROLOGUE();
  const ushort* Ag = pwI + (size_t)m0 * 512;
  const ushort* Bg = ot + ((size_t)b * 1024 + n0) * 512;
  gemm128(Ag, 512, Bg, 512, 512, acc, As, Bs);
  EPILOGUE_IDX();
#pragma unroll
  for (int i = 0; i < 4; ++i)
#pragma unroll
    for (int j = 0; j < 4; ++j)
#pragma unroll
      for (int r = 0; r < 4; ++r) {
        int gm = m0 + wm + i * 16 + ml + r;  // o-channel
        int gn = n0 + wn + j * 16 + nl;      // n-position
        out[((size_t)b * 512 + gm) * 1024 + gn] = acc[i][j][r] + pb[gm];
      }
}

extern "C" void kernel_launch(void* const* d_in, const int* in_sizes, int n_in,
                              void* d_out, int out_size, void* d_ws,
                              size_t ws_size, hipStream_t stream) {
  const float* x = (const float*)d_in[0];
  const float* gw = (const float*)d_in[1];
  const float* gb = (const float*)d_in[2];
  const float* wqkv_f = (const float*)d_in[3];
  const float* bqkv = (const float*)d_in[4];
  const float* pw = (const float*)d_in[5];
  const float* pb = (const float*)d_in[6];
  float* out = (float*)d_out;

  // Workspace layout (84.5 MB peak, region reuse):
  //   0        scale (32KB)
  //   32768    shift (32KB)
  //   65536    pwI bf16 (512KB)
  //   589824   wqkv bf16 (1.5MB)  [1536*512*2]
  //   2162688  R1 (32MB): xt[b][n][c] bf16 (first 16MB); later S[b][n][m]
  //   35717120 R2 (32MB): qk[b][n][0..1024) bf16; later ot[b][n][c] (16MB)
  //   69271552 R3 (16MB): v[b][c][m] bf16
  char* ws = (char*)d_ws;
  float* scale = (float*)(ws + 0);
  float* shift = (float*)(ws + 32768);
  ushort* pwI = (ushort*)(ws + 65536);
  ushort* wqkv = (ushort*)(ws + 589824);
  ushort* xt = (ushort*)(ws + 2162688);
  ushort* S = xt;                       // S overwrites dead xt region
  ushort* qk = (ushort*)(ws + 35717120);
  ushort* ot = qk;                      // ot overwrites dead qk region
  ushort* v = (ushort*)(ws + 69271552);

  gn_stats_k<<<dim3(32, 16), 256, 0, stream>>>(x, gw, gb, scale, shift);
  projw_k<<<dim3(1024), 256, 0, stream>>>(pw, pwI);
  cvt_w_k<<<dim3(3072), 256, 0, stream>>>(wqkv_f, wqkv, 1536 * 512);
  xn_t_k<<<dim3(16, 8, 16), 256, 0, stream>>>(x, scale, shift, xt);
  gemm_qkv_k<<<dim3(8, 12, 16), 256, 0, stream>>>(xt, wqkv, bqkv, qk, v);
  gemm_s_k<<<dim3(8, 8, 16), 256, 0, stream>>>(qk, S);
  softmax_k<<<dim3(4096), 256, 0, stream>>>(S);
  gemm_o_k<<<dim3(8, 4, 16), 256, 0, stream>>>(S, v, ot);
  gemm_proj_k<<<dim3(4, 8, 16), 256, 0, stream>>>(pwI, ot, pb, out);
}

// Round 4
// 238.920 us; speedup vs baseline: 1.1426x; 1.1191x over previous
//
#include <hip/hip_runtime.h>
#include <hip/hip_bf16.h>

// Problem: B=16, C=512, H=W=32 (N=1024), 32 groups (16 ch/group).
// Wire dtype: fp32; internal GEMM dtype: bf16.
// R3->R4: (1) gemm128 is now double-buffered with ONE barrier per K-iter:
//   stage(0); for it: { barrier; stage(it+1 -> alt buf); ds_read+MFMA(cur) }
//   Loads for tile k+1 are in flight during compute of tile k, so the
//   barrier's vmcnt(0) drain stalls latency-minus-compute, not full latency.
// (2) v-tiles of gemm_qkv swap A/B operands to compute D[c][m] directly ->
//   coalesced stores (was 2B scatter at 2KB stride).

typedef __attribute__((ext_vector_type(8))) short bf16x8;   // 8 bf16 = 4 VGPRs
typedef __attribute__((ext_vector_type(4))) float f32x4;

__device__ __forceinline__ float b2f(ushort u) {
  unsigned int v = ((unsigned int)u) << 16;
  float f; __builtin_memcpy(&f, &v, 4); return f;
}
__device__ __forceinline__ ushort f2b(float f) {
  __hip_bfloat16 h = __float2bfloat16(f);
  ushort u; __builtin_memcpy(&u, &h, 2); return u;
}

// async global->LDS, 16B per lane. LDS dest must be wave-uniform base +
// lane*16 (m104/m108); staging index c = ph*256 + w*64 + lane satisfies it.
__device__ __forceinline__ void gld_lds16(const void* g, void* l) {
  auto gp = (const __attribute__((address_space(1))) void*)(uintptr_t)(g);
  auto lp = (__attribute__((address_space(3))) void*)(uintptr_t)(l);
  __builtin_amdgcn_global_load_lds(gp, lp, 16, 0, 0);
}

// ---------------- GroupNorm stats -> per-(b,c) scale/shift ----------------
__global__ __launch_bounds__(256) void gn_stats_k(
    const float* __restrict__ x, const float* __restrict__ gw,
    const float* __restrict__ gb, float* __restrict__ scale,
    float* __restrict__ shift) {
  int g = blockIdx.x, b = blockIdx.y;
  const float* xp = x + ((size_t)b * 512 + g * 16) * 1024;  // 16384 contiguous
  float s = 0.f, ss = 0.f;
  for (int i = threadIdx.x; i < 4096; i += 256) {  // 4096 float4 chunks
    float4 u = ((const float4*)xp)[i];
    s += u.x + u.y + u.z + u.w;
    ss += u.x * u.x + u.y * u.y + u.z * u.z + u.w * u.w;
  }
#pragma unroll
  for (int off = 32; off >= 1; off >>= 1) {
    s += __shfl_xor(s, off); ss += __shfl_xor(ss, off);
  }
  __shared__ float sb[4], ssb[4];
  int w = threadIdx.x >> 6;
  if ((threadIdx.x & 63) == 0) { sb[w] = s; ssb[w] = ss; }
  __syncthreads();
  float st = sb[0] + sb[1] + sb[2] + sb[3];
  float sst = ssb[0] + ssb[1] + ssb[2] + ssb[3];
  float mean = st * (1.f / 16384.f);
  float var = sst * (1.f / 16384.f) - mean * mean;
  float rstd = rsqrtf(var + 1e-5f);
  if (threadIdx.x < 16) {
    int c = g * 16 + threadIdx.x;
    float wc = gw[c];
    scale[b * 512 + c] = rstd * wc;
    shift[b * 512 + c] = gb[c] - mean * rstd * wc;
  }
}

// ---------------- bf16(proj_weight + I) (residual fold) ----------------
__global__ __launch_bounds__(256) void projw_k(const float* __restrict__ pw,
                                               ushort* __restrict__ dst) {
  int i = blockIdx.x * 256 + threadIdx.x;  // 262144 total
  int r = i >> 9, c = i & 511;
  dst[i] = f2b(pw[i] + (r == c ? 1.f : 0.f));
}

// ---------------- normalize + transpose: xn_t[b][n][c] (bf16) ----------------
__global__ __launch_bounds__(256) void xn_t_k(
    const float* __restrict__ x, const float* __restrict__ scale,
    const float* __restrict__ shift, ushort* __restrict__ xt) {
  int b = blockIdx.z, c0 = blockIdx.y * 64, n0 = blockIdx.x * 64;
  __shared__ ushort tile[64][65];
  const float* xp = x + ((size_t)b * 512 + c0) * 1024 + n0;
  int t = threadIdx.x;
  int nq = t & 15, cr = t >> 4;
#pragma unroll
  for (int p = 0; p < 4; ++p) {
    int c = cr + p * 16;
    float4 v = *(const float4*)(xp + (size_t)c * 1024 + nq * 4);
    float sc = scale[b * 512 + c0 + c], sh = shift[b * 512 + c0 + c];
    tile[c][nq * 4 + 0] = f2b(v.x * sc + sh);
    tile[c][nq * 4 + 1] = f2b(v.y * sc + sh);
    tile[c][nq * 4 + 2] = f2b(v.z * sc + sh);
    tile[c][nq * 4 + 3] = f2b(v.w * sc + sh);
  }
  __syncthreads();
  ushort* op = xt + ((size_t)b * 1024 + n0) * 512 + c0;
  int cq = t & 15, nr = t >> 4;
#pragma unroll
  for (int p = 0; p < 4; ++p) {
    int n = nr + p * 16;
    ushort4 u;
    u.x = tile[cq * 4 + 0][n]; u.y = tile[cq * 4 + 1][n];
    u.z = tile[cq * 4 + 2][n]; u.w = tile[cq * 4 + 3][n];
    *(ushort4*)(op + (size_t)n * 512 + cq * 4) = u;
  }
}

// ---------------- shared 128x128 GEMM core: C = A[M][K] . B[N][K]^T ----------
// 256 threads = 4 waves in 2x2; each wave 64x64 via 4x4 mfma_f32_16x16x32_bf16.
// A-frag: m=lane&15, k=(lane>>4)*8+j ; B-frag: n=lane&15, same k (doc-verified).
// Double-buffered: As/Bs are 2 x 8KB; one barrier per K-iter.
__device__ __forceinline__ void gemm128(const ushort* __restrict__ Ag, int lda,
                                        const ushort* __restrict__ Bg, int ldb,
                                        int K, f32x4 (&acc)[4][4], ushort* As,
                                        ushort* Bs) {
  const int t = threadIdx.x;
  const int lane = t & 63, w = t >> 6;
  const int wm = (w >> 1) * 64, wn = (w & 1) * 64;
  const int fr = lane & 15;
  const int fk = (lane >> 4) * 8;
  const int nIter = K >> 5;

  auto stage = [&](int tile) {
    int buf = (tile & 1) * 4096;
    int k0 = tile * 32;
#pragma unroll
    for (int ph = 0; ph < 2; ++ph) {
      int c = ph * 256 + t;
      int r = c >> 2, kc = (c & 3) * 8;
      gld_lds16(Ag + (size_t)r * lda + k0 + kc, As + buf + c * 8);
      gld_lds16(Bg + (size_t)r * ldb + k0 + kc, Bs + buf + c * 8);
    }
  };

  stage(0);
  for (int it = 0; it < nIter; ++it) {
    __syncthreads();  // drains cur-buf loads (in flight since prev iter)
    if (it + 1 < nIter) stage(it + 1);  // async into alt buf, overlaps MFMA
    const int buf = (it & 1) * 4096;
    bf16x8 af[4], bfr[4];
#pragma unroll
    for (int i = 0; i < 4; ++i)
      af[i] = *(const bf16x8*)(As + buf + (wm + i * 16 + fr) * 32 + fk);
#pragma unroll
    for (int j = 0; j < 4; ++j)
      bfr[j] = *(const bf16x8*)(Bs + buf + (wn + j * 16 + fr) * 32 + fk);
#pragma unroll
    for (int i = 0; i < 4; ++i)
#pragma unroll
      for (int j = 0; j < 4; ++j)
        acc[i][j] = __builtin_amdgcn_mfma_f32_16x16x32_bf16(af[i], bfr[j],
                                                            acc[i][j], 0, 0, 0);
  }
}

#define GEMM_PROLOGUE()                                        \
  __shared__ ushort As[8192], Bs[8192];                        \
  f32x4 acc[4][4];                                             \
  { f32x4 z = {0.f, 0.f, 0.f, 0.f};                            \
    _Pragma("unroll") for (int i = 0; i < 4; ++i)              \
      _Pragma("unroll") for (int j = 0; j < 4; ++j) acc[i][j] = z; }

#define EPILOGUE_IDX()                                         \
  int lane = threadIdx.x & 63, w = threadIdx.x >> 6;           \
  int wm = (w >> 1) * 64, wn = (w & 1) * 64;                   \
  int ml = (lane >> 4) * 4, nl = lane & 15;

// ---------------- QKV GEMM ----------------
// q/k o-tiles (n0<1024): D[n][o] = xt . wqkv^T  -> qk[b][n][o]
// v  o-tiles (n0>=1024): operands swapped: D[c][m] = wqkv . xt^T -> v[b][c][m]
__global__ __launch_bounds__(256) void gemm_qkv_k(
    const ushort* __restrict__ xt, const ushort* __restrict__ wqkv,
    const float* __restrict__ bias, ushort* __restrict__ qk,
    ushort* __restrict__ v) {
  int b = blockIdx.z;
  int m0 = blockIdx.x * 128;  // n-position
  int n0 = blockIdx.y * 128;  // output channel (0..1536)
  GEMM_PROLOGUE();
  const ushort* Xg = xt + ((size_t)b * 1024 + m0) * 512;
  const ushort* Wg = wqkv + (size_t)n0 * 512;
  const bool isv = (n0 >= 1024);
  if (!isv)
    gemm128(Xg, 512, Wg, 512, 512, acc, As, Bs);
  else
    gemm128(Wg, 512, Xg, 512, 512, acc, As, Bs);
  EPILOGUE_IDX();
  const float qscale = 0.044194173824159216f;  // 512^-0.5
  if (!isv) {
#pragma unroll
    for (int i = 0; i < 4; ++i)
#pragma unroll
      for (int j = 0; j < 4; ++j) {
        int gn = n0 + wn + j * 16 + nl;  // o-channel
        float bs = bias[gn];
        float sc = (gn < 512) ? qscale : 1.f;
#pragma unroll
        for (int r = 0; r < 4; ++r) {
          int gm = m0 + wm + i * 16 + ml + r;  // n-position
          qk[((size_t)b * 1024 + gm) * 1024 + gn] = f2b((acc[i][j][r] + bs) * sc);
        }
      }
  } else {
#pragma unroll
    for (int i = 0; i < 4; ++i)
#pragma unroll
      for (int j = 0; j < 4; ++j)
#pragma unroll
        for (int r = 0; r < 4; ++r) {
          int c = n0 + wm + i * 16 + ml + r;  // o-channel (1024..1536)
          int m = m0 + wn + j * 16 + nl;      // n-position (coalesced)
          v[((size_t)b * 512 + (c - 1024)) * 1024 + m] =
              f2b(acc[i][j][r] + bias[c]);
        }
  }
}

// ---------------- bf16 qkv_weight staging: wqkv arrives fp32 --------
__global__ __launch_bounds__(256) void cvt_w_k(const float* __restrict__ src,
                                               ushort* __restrict__ dst,
                                               int n) {
  int i = blockIdx.x * 256 + threadIdx.x;
  if (i < n) dst[i] = f2b(src[i]);
}

// ---------------- S GEMM: S[n][m] = q_t . k_t^T ----------------
__global__ __launch_bounds__(256) void gemm_s_k(const ushort* __restrict__ qk,
                                                ushort* __restrict__ S) {
  int b = blockIdx.z;
  int m0 = blockIdx.x * 128, n0 = blockIdx.y * 128;
  GEMM_PROLOGUE();
  const ushort* Ag = qk + ((size_t)b * 1024 + m0) * 1024;        // q cols 0..512
  const ushort* Bg = qk + ((size_t)b * 1024 + n0) * 1024 + 512;  // k cols 512..1024
  gemm128(Ag, 1024, Bg, 1024, 512, acc, As, Bs);
  EPILOGUE_IDX();
#pragma unroll
  for (int i = 0; i < 4; ++i)
#pragma unroll
    for (int j = 0; j < 4; ++j)
#pragma unroll
      for (int r = 0; r < 4; ++r) {
        int gm = m0 + wm + i * 16 + ml + r, gn = n0 + wn + j * 16 + nl;
        S[((size_t)b * 1024 + gm) * 1024 + gn] = f2b(acc[i][j][r]);
      }
}

// ---------------- rowwise softmax in place (wave per row, bf16) ----------------
__global__ __launch_bounds__(256) void softmax_k(ushort* __restrict__ S) {
  int row = blockIdx.x * 4 + (threadIdx.x >> 6);
  int lane = threadIdx.x & 63;
  ushort* p = S + (size_t)row * 1024 + lane * 16;
  uint4 u0 = *(uint4*)p, u1 = *(uint4*)(p + 8);
  float v[16];
  const ushort* e0 = (const ushort*)&u0;
  const ushort* e1 = (const ushort*)&u1;
#pragma unroll
  for (int j = 0; j < 8; ++j) { v[j] = b2f(e0[j]); v[8 + j] = b2f(e1[j]); }
  float m = v[0];
#pragma unroll
  for (int j = 1; j < 16; ++j) m = fmaxf(m, v[j]);
#pragma unroll
  for (int off = 32; off >= 1; off >>= 1) m = fmaxf(m, __shfl_xor(m, off));
  float s = 0.f;
#pragma unroll
  for (int j = 0; j < 16; ++j) { v[j] = __expf(v[j] - m); s += v[j]; }
#pragma unroll
  for (int off = 32; off >= 1; off >>= 1) s += __shfl_xor(s, off);
  float inv = 1.f / s;
  uint4 r4[2];
  ushort* r = (ushort*)r4;
#pragma unroll
  for (int j = 0; j < 16; ++j) r[j] = f2b(v[j] * inv);
  *(uint4*)p = r4[0];
  *(uint4*)(p + 8) = r4[1];
}

// ---------------- O GEMM: ot[n][c] = P . v^T ----------------
__global__ __launch_bounds__(256) void gemm_o_k(const ushort* __restrict__ S,
                                                const ushort* __restrict__ v,
                                                ushort* __restrict__ ot) {
  int b = blockIdx.z;
  int m0 = blockIdx.x * 128;  // n-position
  int n0 = blockIdx.y * 128;  // channel (0..512)
  GEMM_PROLOGUE();
  const ushort* Ag = S + ((size_t)b * 1024 + m0) * 1024;
  const ushort* Bg = v + ((size_t)b * 512 + n0) * 1024;
  gemm128(Ag, 1024, Bg, 1024, 1024, acc, As, Bs);
  EPILOGUE_IDX();
#pragma unroll
  for (int i = 0; i < 4; ++i)
#pragma unroll
    for (int j = 0; j < 4; ++j)
#pragma unroll
      for (int r = 0; r < 4; ++r) {
        int gm = m0 + wm + i * 16 + ml + r, gn = n0 + wn + j * 16 + nl;
        ot[((size_t)b * 1024 + gm) * 512 + gn] = f2b(acc[i][j][r]);
      }
}

// ---------------- proj GEMM: out[o][n] = (Wp+I) . ot^T + bias (fp32 out) ----
__global__ __launch_bounds__(256) void gemm_proj_k(
    const ushort* __restrict__ pwI, const ushort* __restrict__ ot,
    const float* __restrict__ pb, float* __restrict__ out) {
  int b = blockIdx.z;
  int m0 = blockIdx.x * 128;  // o-channel (0..512)
  int n0 = blockIdx.y * 128;  // n-position
  GEMM_PROLOGUE();
  const ushort* Ag = pwI + (size_t)m0 * 512;
  const ushort* Bg = ot + ((size_t)b * 1024 + n0) * 512;
  gemm128(Ag, 512, Bg, 512, 512, acc, As, Bs);
  EPILOGUE_IDX();
#pragma unroll
  for (int i = 0; i < 4; ++i)
#pragma unroll
    for (int j = 0; j < 4; ++j)
#pragma unroll
      for (int r = 0; r < 4; ++r) {
        int gm = m0 + wm + i * 16 + ml + r;  // o-channel
        int gn = n0 + wn + j * 16 + nl;      // n-position
        out[((size_t)b * 512 + gm) * 1024 + gn] = acc[i][j][r] + pb[gm];
      }
}

extern "C" void kernel_launch(void* const* d_in, const int* in_sizes, int n_in,
                              void* d_out, int out_size, void* d_ws,
                              size_t ws_size, hipStream_t stream) {
  const float* x = (const float*)d_in[0];
  const float* gw = (const float*)d_in[1];
  const float* gb = (const float*)d_in[2];
  const float* wqkv_f = (const float*)d_in[3];
  const float* bqkv = (const float*)d_in[4];
  const float* pw = (const float*)d_in[5];
  const float* pb = (const float*)d_in[6];
  float* out = (float*)d_out;

  // Workspace layout (84.5 MB peak, region reuse):
  //   0        scale (32KB)
  //   32768    shift (32KB)
  //   65536    pwI bf16 (512KB)
  //   589824   wqkv bf16 (1.5MB)  [1536*512*2]
  //   2162688  R1 (32MB): xt[b][n][c] bf16 (first 16MB); later S[b][n][m]
  //   35717120 R2 (32MB): qk[b][n][0..1024) bf16; later ot[b][n][c] (16MB)
  //   69271552 R3 (16MB): v[b][c][m] bf16
  char* ws = (char*)d_ws;
  float* scale = (float*)(ws + 0);
  float* shift = (float*)(ws + 32768);
  ushort* pwI = (ushort*)(ws + 65536);
  ushort* wqkv = (ushort*)(ws + 589824);
  ushort* xt = (ushort*)(ws + 2162688);
  ushort* S = xt;                       // S overwrites dead xt region
  ushort* qk = (ushort*)(ws + 35717120);
  ushort* ot = qk;                      // ot overwrites dead qk region
  ushort* v = (ushort*)(ws + 69271552);

  gn_stats_k<<<dim3(32, 16), 256, 0, stream>>>(x, gw, gb, scale, shift);
  projw_k<<<dim3(1024), 256, 0, stream>>>(pw, pwI);
  cvt_w_k<<<dim3(3072), 256, 0, stream>>>(wqkv_f, wqkv, 1536 * 512);
  xn_t_k<<<dim3(16, 8, 16), 256, 0, stream>>>(x, scale, shift, xt);
  gemm_qkv_k<<<dim3(8, 12, 16), 256, 0, stream>>>(xt, wqkv, bqkv, qk, v);
  gemm_s_k<<<dim3(8, 8, 16), 256, 0, stream>>>(qk, S);
  softmax_k<<<dim3(4096), 256, 0, stream>>>(S);
  gemm_o_k<<<dim3(8, 4, 16), 256, 0, stream>>>(S, v, ot);
  gemm_proj_k<<<dim3(4, 8, 16), 256, 0, stream>>>(pwI, ot, pb, out);
}

// Round 5
// 231.716 us; speedup vs baseline: 1.1781x; 1.0311x over previous
//
#include <hip/hip_runtime.h>
#include <hip/hip_bf16.h>

// Problem: B=16, C=512, H=W=32 (N=1024), 32 groups (16 ch/group).
// Wire dtype: fp32; internal GEMM dtype: bf16.
// R4->R5: gemm128 K-loop restructured AITER-style: triple-buffered LDS,
//   2 tiles in flight, explicit `s_waitcnt vmcnt(4)` (waits only the 4
//   oldest global_load_lds ops = the tile about to be consumed) + raw
//   s_barrier. Never vmcnt(0) inside the loop -> prefetch stays in flight
//   across the barrier (the compiler's __syncthreads vmcnt(0) drain was
//   capping pipeline depth at one compute-phase).

typedef __attribute__((ext_vector_type(8))) short bf16x8;   // 8 bf16 = 4 VGPRs
typedef __attribute__((ext_vector_type(4))) float f32x4;

__device__ __forceinline__ float b2f(ushort u) {
  unsigned int v = ((unsigned int)u) << 16;
  float f; __builtin_memcpy(&f, &v, 4); return f;
}
__device__ __forceinline__ ushort f2b(float f) {
  __hip_bfloat16 h = __float2bfloat16(f);
  ushort u; __builtin_memcpy(&u, &h, 2); return u;
}

// async global->LDS, 16B per lane. LDS dest must be wave-uniform base +
// lane*16 (m104/m108); staging index c = ph*256 + w*64 + lane satisfies it.
__device__ __forceinline__ void gld_lds16(const void* g, void* l) {
  auto gp = (const __attribute__((address_space(1))) void*)(uintptr_t)(g);
  auto lp = (__attribute__((address_space(3))) void*)(uintptr_t)(l);
  __builtin_amdgcn_global_load_lds(gp, lp, 16, 0, 0);
}

// ---------------- GroupNorm stats -> per-(b,c) scale/shift ----------------
__global__ __launch_bounds__(256) void gn_stats_k(
    const float* __restrict__ x, const float* __restrict__ gw,
    const float* __restrict__ gb, float* __restrict__ scale,
    float* __restrict__ shift) {
  int g = blockIdx.x, b = blockIdx.y;
  const float* xp = x + ((size_t)b * 512 + g * 16) * 1024;  // 16384 contiguous
  float s = 0.f, ss = 0.f;
  for (int i = threadIdx.x; i < 4096; i += 256) {  // 4096 float4 chunks
    float4 u = ((const float4*)xp)[i];
    s += u.x + u.y + u.z + u.w;
    ss += u.x * u.x + u.y * u.y + u.z * u.z + u.w * u.w;
  }
#pragma unroll
  for (int off = 32; off >= 1; off >>= 1) {
    s += __shfl_xor(s, off); ss += __shfl_xor(ss, off);
  }
  __shared__ float sb[4], ssb[4];
  int w = threadIdx.x >> 6;
  if ((threadIdx.x & 63) == 0) { sb[w] = s; ssb[w] = ss; }
  __syncthreads();
  float st = sb[0] + sb[1] + sb[2] + sb[3];
  float sst = ssb[0] + ssb[1] + ssb[2] + ssb[3];
  float mean = st * (1.f / 16384.f);
  float var = sst * (1.f / 16384.f) - mean * mean;
  float rstd = rsqrtf(var + 1e-5f);
  if (threadIdx.x < 16) {
    int c = g * 16 + threadIdx.x;
    float wc = gw[c];
    scale[b * 512 + c] = rstd * wc;
    shift[b * 512 + c] = gb[c] - mean * rstd * wc;
  }
}

// ---------------- bf16(proj_weight + I) (residual fold) ----------------
__global__ __launch_bounds__(256) void projw_k(const float* __restrict__ pw,
                                               ushort* __restrict__ dst) {
  int i = blockIdx.x * 256 + threadIdx.x;  // 262144 total
  int r = i >> 9, c = i & 511;
  dst[i] = f2b(pw[i] + (r == c ? 1.f : 0.f));
}

// ---------------- normalize + transpose: xn_t[b][n][c] (bf16) ----------------
__global__ __launch_bounds__(256) void xn_t_k(
    const float* __restrict__ x, const float* __restrict__ scale,
    const float* __restrict__ shift, ushort* __restrict__ xt) {
  int b = blockIdx.z, c0 = blockIdx.y * 64, n0 = blockIdx.x * 64;
  __shared__ ushort tile[64][65];
  const float* xp = x + ((size_t)b * 512 + c0) * 1024 + n0;
  int t = threadIdx.x;
  int nq = t & 15, cr = t >> 4;
#pragma unroll
  for (int p = 0; p < 4; ++p) {
    int c = cr + p * 16;
    float4 v = *(const float4*)(xp + (size_t)c * 1024 + nq * 4);
    float sc = scale[b * 512 + c0 + c], sh = shift[b * 512 + c0 + c];
    tile[c][nq * 4 + 0] = f2b(v.x * sc + sh);
    tile[c][nq * 4 + 1] = f2b(v.y * sc + sh);
    tile[c][nq * 4 + 2] = f2b(v.z * sc + sh);
    tile[c][nq * 4 + 3] = f2b(v.w * sc + sh);
  }
  __syncthreads();
  ushort* op = xt + ((size_t)b * 1024 + n0) * 512 + c0;
  int cq = t & 15, nr = t >> 4;
#pragma unroll
  for (int p = 0; p < 4; ++p) {
    int n = nr + p * 16;
    ushort4 u;
    u.x = tile[cq * 4 + 0][n]; u.y = tile[cq * 4 + 1][n];
    u.z = tile[cq * 4 + 2][n]; u.w = tile[cq * 4 + 3][n];
    *(ushort4*)(op + (size_t)n * 512 + cq * 4) = u;
  }
}

// ---------------- shared 128x128 GEMM core: C = A[M][K] . B[N][K]^T ----------
// 256 threads = 4 waves in 2x2; each wave 64x64 via 4x4 mfma_f32_16x16x32_bf16.
// A-frag: m=lane&15, k=(lane>>4)*8+j ; B-frag: n=lane&15, same k (doc-verified).
// Triple-buffered (3 x 8KB per matrix), 2 tiles in flight, one raw barrier
// per K-iter with s_waitcnt vmcnt(4) (each stage = 4 gld_lds16 per thread).
__device__ __forceinline__ void gemm128(const ushort* __restrict__ Ag, int lda,
                                        const ushort* __restrict__ Bg, int ldb,
                                        int K, f32x4 (&acc)[4][4], ushort* As,
                                        ushort* Bs) {
  const int t = threadIdx.x;
  const int lane = t & 63, w = t >> 6;
  const int wm = (w >> 1) * 64, wn = (w & 1) * 64;
  const int fr = lane & 15;
  const int fk = (lane >> 4) * 8;
  const int nIter = K >> 5;

  auto stage = [&](int tile) {
    int buf = (tile % 3) * 4096;  // ushort offset: 8KB per buffer
    int k0 = tile * 32;
#pragma unroll
    for (int ph = 0; ph < 2; ++ph) {
      int c = ph * 256 + t;
      int r = c >> 2, kc = (c & 3) * 8;
      gld_lds16(Ag + (size_t)r * lda + k0 + kc, As + buf + c * 8);
      gld_lds16(Bg + (size_t)r * ldb + k0 + kc, Bs + buf + c * 8);
    }
  };

  stage(0);
  stage(1);  // 8 loads/thread in flight
  for (int it = 0; it < nIter; ++it) {
    // Wait only for the oldest stage (the tile we're about to consume);
    // the newer stage (<=4 ops) stays in flight across the barrier.
    if (it + 1 < nIter) {
      asm volatile("s_waitcnt vmcnt(4)" ::: "memory");
    } else {
      asm volatile("s_waitcnt vmcnt(0)" ::: "memory");
    }
    __builtin_amdgcn_s_barrier();
    asm volatile("" ::: "memory");
    if (it + 2 < nIter) stage(it + 2);  // async into buf[(it+2)%3]
    const int buf = (it % 3) * 4096;
    bf16x8 af[4], bfr[4];
#pragma unroll
    for (int i = 0; i < 4; ++i)
      af[i] = *(const bf16x8*)(As + buf + (wm + i * 16 + fr) * 32 + fk);
#pragma unroll
    for (int j = 0; j < 4; ++j)
      bfr[j] = *(const bf16x8*)(Bs + buf + (wn + j * 16 + fr) * 32 + fk);
#pragma unroll
    for (int i = 0; i < 4; ++i)
#pragma unroll
      for (int j = 0; j < 4; ++j)
        acc[i][j] = __builtin_amdgcn_mfma_f32_16x16x32_bf16(af[i], bfr[j],
                                                            acc[i][j], 0, 0, 0);
  }
}

#define GEMM_PROLOGUE()                                        \
  __shared__ ushort As[12288], Bs[12288];                      \
  f32x4 acc[4][4];                                             \
  { f32x4 z = {0.f, 0.f, 0.f, 0.f};                            \
    _Pragma("unroll") for (int i = 0; i < 4; ++i)              \
      _Pragma("unroll") for (int j = 0; j < 4; ++j) acc[i][j] = z; }

#define EPILOGUE_IDX()                                         \
  int lane = threadIdx.x & 63, w = threadIdx.x >> 6;           \
  int wm = (w >> 1) * 64, wn = (w & 1) * 64;                   \
  int ml = (lane >> 4) * 4, nl = lane & 15;

// ---------------- QKV GEMM ----------------
// q/k o-tiles (n0<1024): D[n][o] = xt . wqkv^T  -> qk[b][n][o]
// v  o-tiles (n0>=1024): operands swapped: D[c][m] = wqkv . xt^T -> v[b][c][m]
__global__ __launch_bounds__(256) void gemm_qkv_k(
    const ushort* __restrict__ xt, const ushort* __restrict__ wqkv,
    const float* __restrict__ bias, ushort* __restrict__ qk,
    ushort* __restrict__ v) {
  int b = blockIdx.z;
  int m0 = blockIdx.x * 128;  // n-position
  int n0 = blockIdx.y * 128;  // output channel (0..1536)
  GEMM_PROLOGUE();
  const ushort* Xg = xt + ((size_t)b * 1024 + m0) * 512;
  const ushort* Wg = wqkv + (size_t)n0 * 512;
  const bool isv = (n0 >= 1024);
  if (!isv)
    gemm128(Xg, 512, Wg, 512, 512, acc, As, Bs);
  else
    gemm128(Wg, 512, Xg, 512, 512, acc, As, Bs);
  EPILOGUE_IDX();
  const float qscale = 0.044194173824159216f;  // 512^-0.5
  if (!isv) {
#pragma unroll
    for (int i = 0; i < 4; ++i)
#pragma unroll
      for (int j = 0; j < 4; ++j) {
        int gn = n0 + wn + j * 16 + nl;  // o-channel
        float bs = bias[gn];
        float sc = (gn < 512) ? qscale : 1.f;
#pragma unroll
        for (int r = 0; r < 4; ++r) {
          int gm = m0 + wm + i * 16 + ml + r;  // n-position
          qk[((size_t)b * 1024 + gm) * 1024 + gn] = f2b((acc[i][j][r] + bs) * sc);
        }
      }
  } else {
#pragma unroll
    for (int i = 0; i < 4; ++i)
#pragma unroll
      for (int j = 0; j < 4; ++j)
#pragma unroll
        for (int r = 0; r < 4; ++r) {
          int c = n0 + wm + i * 16 + ml + r;  // o-channel (1024..1536)
          int m = m0 + wn + j * 16 + nl;      // n-position (coalesced)
          v[((size_t)b * 512 + (c - 1024)) * 1024 + m] =
              f2b(acc[i][j][r] + bias[c]);
        }
  }
}

// ---------------- bf16 qkv_weight staging: wqkv arrives fp32 --------
__global__ __launch_bounds__(256) void cvt_w_k(const float* __restrict__ src,
                                               ushort* __restrict__ dst,
                                               int n) {
  int i = blockIdx.x * 256 + threadIdx.x;
  if (i < n) dst[i] = f2b(src[i]);
}

// ---------------- S GEMM: S[n][m] = q_t . k_t^T ----------------
__global__ __launch_bounds__(256) void gemm_s_k(const ushort* __restrict__ qk,
                                                ushort* __restrict__ S) {
  int b = blockIdx.z;
  int m0 = blockIdx.x * 128, n0 = blockIdx.y * 128;
  GEMM_PROLOGUE();
  const ushort* Ag = qk + ((size_t)b * 1024 + m0) * 1024;        // q cols 0..512
  const ushort* Bg = qk + ((size_t)b * 1024 + n0) * 1024 + 512;  // k cols 512..1024
  gemm128(Ag, 1024, Bg, 1024, 512, acc, As, Bs);
  EPILOGUE_IDX();
#pragma unroll
  for (int i = 0; i < 4; ++i)
#pragma unroll
    for (int j = 0; j < 4; ++j)
#pragma unroll
      for (int r = 0; r < 4; ++r) {
        int gm = m0 + wm + i * 16 + ml + r, gn = n0 + wn + j * 16 + nl;
        S[((size_t)b * 1024 + gm) * 1024 + gn] = f2b(acc[i][j][r]);
      }
}

// ---------------- rowwise softmax in place (wave per row, bf16) ----------------
__global__ __launch_bounds__(256) void softmax_k(ushort* __restrict__ S) {
  int row = blockIdx.x * 4 + (threadIdx.x >> 6);
  int lane = threadIdx.x & 63;
  ushort* p = S + (size_t)row * 1024 + lane * 16;
  uint4 u0 = *(uint4*)p, u1 = *(uint4*)(p + 8);
  float v[16];
  const ushort* e0 = (const ushort*)&u0;
  const ushort* e1 = (const ushort*)&u1;
#pragma unroll
  for (int j = 0; j < 8; ++j) { v[j] = b2f(e0[j]); v[8 + j] = b2f(e1[j]); }
  float m = v[0];
#pragma unroll
  for (int j = 1; j < 16; ++j) m = fmaxf(m, v[j]);
#pragma unroll
  for (int off = 32; off >= 1; off >>= 1) m = fmaxf(m, __shfl_xor(m, off));
  float s = 0.f;
#pragma unroll
  for (int j = 0; j < 16; ++j) { v[j] = __expf(v[j] - m); s += v[j]; }
#pragma unroll
  for (int off = 32; off >= 1; off >>= 1) s += __shfl_xor(s, off);
  float inv = 1.f / s;
  uint4 r4[2];
  ushort* r = (ushort*)r4;
#pragma unroll
  for (int j = 0; j < 16; ++j) r[j] = f2b(v[j] * inv);
  *(uint4*)p = r4[0];
  *(uint4*)(p + 8) = r4[1];
}

// ---------------- O GEMM: ot[n][c] = P . v^T ----------------
__global__ __launch_bounds__(256) void gemm_o_k(const ushort* __restrict__ S,
                                                const ushort* __restrict__ v,
                                                ushort* __restrict__ ot) {
  int b = blockIdx.z;
  int m0 = blockIdx.x * 128;  // n-position
  int n0 = blockIdx.y * 128;  // channel (0..512)
  GEMM_PROLOGUE();
  const ushort* Ag = S + ((size_t)b * 1024 + m0) * 1024;
  const ushort* Bg = v + ((size_t)b * 512 + n0) * 1024;
  gemm128(Ag, 1024, Bg, 1024, 1024, acc, As, Bs);
  EPILOGUE_IDX();
#pragma unroll
  for (int i = 0; i < 4; ++i)
#pragma unroll
    for (int j = 0; j < 4; ++j)
#pragma unroll
      for (int r = 0; r < 4; ++r) {
        int gm = m0 + wm + i * 16 + ml + r, gn = n0 + wn + j * 16 + nl;
        ot[((size_t)b * 1024 + gm) * 512 + gn] = f2b(acc[i][j][r]);
      }
}

// ---------------- proj GEMM: out[o][n] = (Wp+I) . ot^T + bias (fp32 out) ----
__global__ __launch_bounds__(256) void gemm_proj_k(
    const ushort* __restrict__ pwI, const ushort* __restrict__ ot,
    const float* __restrict__ pb, float* __restrict__ out) {
  int b = blockIdx.z;
  int m0 = blockIdx.x * 128;  // o-channel (0..512)
  int n0 = blockIdx.y * 128;  // n-position
  GEMM_PROLOGUE();
  const ushort* Ag = pwI + (size_t)m0 * 512;
  const ushort* Bg = ot + ((size_t)b * 1024 + n0) * 512;
  gemm128(Ag, 512, Bg, 512, 512, acc, As, Bs);
  EPILOGUE_IDX();
#pragma unroll
  for (int i = 0; i < 4; ++i)
#pragma unroll
    for (int j = 0; j < 4; ++j)
#pragma unroll
      for (int r = 0; r < 4; ++r) {
        int gm = m0 + wm + i * 16 + ml + r;  // o-channel
        int gn = n0 + wn + j * 16 + nl;      // n-position
        out[((size_t)b * 512 + gm) * 1024 + gn] = acc[i][j][r] + pb[gm];
      }
}

extern "C" void kernel_launch(void* const* d_in, const int* in_sizes, int n_in,
                              void* d_out, int out_size, void* d_ws,
                              size_t ws_size, hipStream_t stream) {
  const float* x = (const float*)d_in[0];
  const float* gw = (const float*)d_in[1];
  const float* gb = (const float*)d_in[2];
  const float* wqkv_f = (const float*)d_in[3];
  const float* bqkv = (const float*)d_in[4];
  const float* pw = (const float*)d_in[5];
  const float* pb = (const float*)d_in[6];
  float* out = (float*)d_out;

  // Workspace layout (84.5 MB peak, region reuse):
  //   0        scale (32KB)
  //   32768    shift (32KB)
  //   65536    pwI bf16 (512KB)
  //   589824   wqkv bf16 (1.5MB)  [1536*512*2]
  //   2162688  R1 (32MB): xt[b][n][c] bf16 (first 16MB); later S[b][n][m]
  //   35717120 R2 (32MB): qk[b][n][0..1024) bf16; later ot[b][n][c] (16MB)
  //   69271552 R3 (16MB): v[b][c][m] bf16
  char* ws = (char*)d_ws;
  float* scale = (float*)(ws + 0);
  float* shift = (float*)(ws + 32768);
  ushort* pwI = (ushort*)(ws + 65536);
  ushort* wqkv = (ushort*)(ws + 589824);
  ushort* xt = (ushort*)(ws + 2162688);
  ushort* S = xt;                       // S overwrites dead xt region
  ushort* qk = (ushort*)(ws + 35717120);
  ushort* ot = qk;                      // ot overwrites dead qk region
  ushort* v = (ushort*)(ws + 69271552);

  gn_stats_k<<<dim3(32, 16), 256, 0, stream>>>(x, gw, gb, scale, shift);
  projw_k<<<dim3(1024), 256, 0, stream>>>(pw, pwI);
  cvt_w_k<<<dim3(3072), 256, 0, stream>>>(wqkv_f, wqkv, 1536 * 512);
  xn_t_k<<<dim3(16, 8, 16), 256, 0, stream>>>(x, scale, shift, xt);
  gemm_qkv_k<<<dim3(8, 12, 16), 256, 0, stream>>>(xt, wqkv, bqkv, qk, v);
  gemm_s_k<<<dim3(8, 8, 16), 256, 0, stream>>>(qk, S);
  softmax_k<<<dim3(4096), 256, 0, stream>>>(S);
  gemm_o_k<<<dim3(8, 4, 16), 256, 0, stream>>>(S, v, ot);
  gemm_proj_k<<<dim3(4, 8, 16), 256, 0, stream>>>(pwI, ot, pb, out);
}

// Round 6
// 224.630 us; speedup vs baseline: 1.2153x; 1.0315x over previous
//
#include <hip/hip_runtime.h>
#include <hip/hip_bf16.h>

// Problem: B=16, C=512, H=W=32 (N=1024), 32 groups (16 ch/group).
// Wire dtype: fp32; internal GEMM dtype: bf16.
// R5->R6: (1) gemm128 takes K as a template arg -> full unroll, compile-time
//   buffer rotation (%3) and stage addresses (kills per-iter VALU/SALU).
//   (2) gn_stats + projw + cvt_w merged into one prep_k (9 -> 7 launches).

typedef __attribute__((ext_vector_type(8))) short bf16x8;   // 8 bf16 = 4 VGPRs
typedef __attribute__((ext_vector_type(4))) float f32x4;

__device__ __forceinline__ float b2f(ushort u) {
  unsigned int v = ((unsigned int)u) << 16;
  float f; __builtin_memcpy(&f, &v, 4); return f;
}
__device__ __forceinline__ ushort f2b(float f) {
  __hip_bfloat16 h = __float2bfloat16(f);
  ushort u; __builtin_memcpy(&u, &h, 2); return u;
}

// async global->LDS, 16B per lane. LDS dest must be wave-uniform base +
// lane*16 (m104/m108); staging index c = ph*256 + w*64 + lane satisfies it.
__device__ __forceinline__ void gld_lds16(const void* g, void* l) {
  auto gp = (const __attribute__((address_space(1))) void*)(uintptr_t)(g);
  auto lp = (__attribute__((address_space(3))) void*)(uintptr_t)(l);
  __builtin_amdgcn_global_load_lds(gp, lp, 16, 0, 0);
}

// ---------------- fused prep: GN stats | proj_weight+I | qkv_weight cvt ----
// Block-uniform branch on blockIdx.x ranges.
__global__ __launch_bounds__(256) void prep_k(
    const float* __restrict__ x, const float* __restrict__ gw,
    const float* __restrict__ gb, float* __restrict__ scale,
    float* __restrict__ shift, const float* __restrict__ pw,
    ushort* __restrict__ pwI, const float* __restrict__ wqkv_f,
    ushort* __restrict__ wqkv) {
  __shared__ float sb[4], ssb[4];
  int blk = blockIdx.x;
  if (blk < 512) {  // ---- GN stats: b = blk>>5, g = blk&31
    int b = blk >> 5, g = blk & 31;
    const float* xp = x + ((size_t)b * 512 + g * 16) * 1024;
    float s = 0.f, ss = 0.f;
    for (int i = threadIdx.x; i < 4096; i += 256) {
      float4 u = ((const float4*)xp)[i];
      s += u.x + u.y + u.z + u.w;
      ss += u.x * u.x + u.y * u.y + u.z * u.z + u.w * u.w;
    }
#pragma unroll
    for (int off = 32; off >= 1; off >>= 1) {
      s += __shfl_xor(s, off); ss += __shfl_xor(ss, off);
    }
    int w = threadIdx.x >> 6;
    if ((threadIdx.x & 63) == 0) { sb[w] = s; ssb[w] = ss; }
    __syncthreads();
    float st = sb[0] + sb[1] + sb[2] + sb[3];
    float sst = ssb[0] + ssb[1] + ssb[2] + ssb[3];
    float mean = st * (1.f / 16384.f);
    float var = sst * (1.f / 16384.f) - mean * mean;
    float rstd = rsqrtf(var + 1e-5f);
    if (threadIdx.x < 16) {
      int c = g * 16 + threadIdx.x;
      float wc = gw[c];
      scale[b * 512 + c] = rstd * wc;
      shift[b * 512 + c] = gb[c] - mean * rstd * wc;
    }
  } else if (blk < 1536) {  // ---- pwI = bf16(proj_weight + I), 262144 elems
    int i = (blk - 512) * 256 + threadIdx.x;
    int r = i >> 9, c = i & 511;
    pwI[i] = f2b(pw[i] + (r == c ? 1.f : 0.f));
  } else {  // ---- wqkv bf16 convert, 786432 elems, blocks 1536..4607
    int i = (blk - 1536) * 256 + threadIdx.x;
    wqkv[i] = f2b(wqkv_f[i]);
  }
}

// ---------------- normalize + transpose: xn_t[b][n][c] (bf16) ----------------
__global__ __launch_bounds__(256) void xn_t_k(
    const float* __restrict__ x, const float* __restrict__ scale,
    const float* __restrict__ shift, ushort* __restrict__ xt) {
  int b = blockIdx.z, c0 = blockIdx.y * 64, n0 = blockIdx.x * 64;
  __shared__ ushort tile[64][65];
  const float* xp = x + ((size_t)b * 512 + c0) * 1024 + n0;
  int t = threadIdx.x;
  int nq = t & 15, cr = t >> 4;
#pragma unroll
  for (int p = 0; p < 4; ++p) {
    int c = cr + p * 16;
    float4 v = *(const float4*)(xp + (size_t)c * 1024 + nq * 4);
    float sc = scale[b * 512 + c0 + c], sh = shift[b * 512 + c0 + c];
    tile[c][nq * 4 + 0] = f2b(v.x * sc + sh);
    tile[c][nq * 4 + 1] = f2b(v.y * sc + sh);
    tile[c][nq * 4 + 2] = f2b(v.z * sc + sh);
    tile[c][nq * 4 + 3] = f2b(v.w * sc + sh);
  }
  __syncthreads();
  ushort* op = xt + ((size_t)b * 1024 + n0) * 512 + c0;
  int cq = t & 15, nr = t >> 4;
#pragma unroll
  for (int p = 0; p < 4; ++p) {
    int n = nr + p * 16;
    ushort4 u;
    u.x = tile[cq * 4 + 0][n]; u.y = tile[cq * 4 + 1][n];
    u.z = tile[cq * 4 + 2][n]; u.w = tile[cq * 4 + 3][n];
    *(ushort4*)(op + (size_t)n * 512 + cq * 4) = u;
  }
}

// ---------------- shared 128x128 GEMM core: C = A[M][K] . B[N][K]^T ----------
// 256 threads = 4 waves in 2x2; each wave 64x64 via 4x4 mfma_f32_16x16x32_bf16.
// A-frag: m=lane&15, k=(lane>>4)*8+j ; B-frag: n=lane&15, same k (doc-verified).
// Triple-buffered (3 x 8KB per matrix), 2 tiles in flight, one raw barrier
// per K-iter with s_waitcnt vmcnt(4). K templated -> full unroll, constant
// buffer rotation and addresses.
template <int K>
__device__ __forceinline__ void gemm128(const ushort* __restrict__ Ag, int lda,
                                        const ushort* __restrict__ Bg, int ldb,
                                        f32x4 (&acc)[4][4], ushort* As,
                                        ushort* Bs) {
  const int t = threadIdx.x;
  const int lane = t & 63, w = t >> 6;
  const int wm = (w >> 1) * 64, wn = (w & 1) * 64;
  const int fr = lane & 15;
  const int fk = (lane >> 4) * 8;
  constexpr int nIter = K >> 5;

  auto stage = [&](int tile) {
    int buf = (tile % 3) * 4096;  // ushort offset: 8KB per buffer
    int k0 = tile * 32;
#pragma unroll
    for (int ph = 0; ph < 2; ++ph) {
      int c = ph * 256 + t;
      int r = c >> 2, kc = (c & 3) * 8;
      gld_lds16(Ag + (size_t)r * lda + k0 + kc, As + buf + c * 8);
      gld_lds16(Bg + (size_t)r * ldb + k0 + kc, Bs + buf + c * 8);
    }
  };

  stage(0);
  stage(1);  // 8 loads/thread in flight
#pragma unroll
  for (int it = 0; it < nIter; ++it) {
    // Wait only for the oldest stage (the tile we're about to consume);
    // the newer stage (<=4 ops) stays in flight across the barrier.
    if (it + 1 < nIter) {
      asm volatile("s_waitcnt vmcnt(4)" ::: "memory");
    } else {
      asm volatile("s_waitcnt vmcnt(0)" ::: "memory");
    }
    __builtin_amdgcn_s_barrier();
    asm volatile("" ::: "memory");
    if (it + 2 < nIter) stage(it + 2);  // async into buf[(it+2)%3]
    const int buf = (it % 3) * 4096;
    bf16x8 af[4], bfr[4];
#pragma unroll
    for (int i = 0; i < 4; ++i)
      af[i] = *(const bf16x8*)(As + buf + (wm + i * 16 + fr) * 32 + fk);
#pragma unroll
    for (int j = 0; j < 4; ++j)
      bfr[j] = *(const bf16x8*)(Bs + buf + (wn + j * 16 + fr) * 32 + fk);
#pragma unroll
    for (int i = 0; i < 4; ++i)
#pragma unroll
      for (int j = 0; j < 4; ++j)
        acc[i][j] = __builtin_amdgcn_mfma_f32_16x16x32_bf16(af[i], bfr[j],
                                                            acc[i][j], 0, 0, 0);
  }
}

#define GEMM_PROLOGUE()                                        \
  __shared__ ushort As[12288], Bs[12288];                      \
  f32x4 acc[4][4];                                             \
  { f32x4 z = {0.f, 0.f, 0.f, 0.f};                            \
    _Pragma("unroll") for (int i = 0; i < 4; ++i)              \
      _Pragma("unroll") for (int j = 0; j < 4; ++j) acc[i][j] = z; }

#define EPILOGUE_IDX()                                         \
  int lane = threadIdx.x & 63, w = threadIdx.x >> 6;           \
  int wm = (w >> 1) * 64, wn = (w & 1) * 64;                   \
  int ml = (lane >> 4) * 4, nl = lane & 15;

// ---------------- QKV GEMM ----------------
// q/k o-tiles (n0<1024): D[n][o] = xt . wqkv^T  -> qk[b][n][o]
// v  o-tiles (n0>=1024): operands swapped: D[c][m] = wqkv . xt^T -> v[b][c][m]
__global__ __launch_bounds__(256) void gemm_qkv_k(
    const ushort* __restrict__ xt, const ushort* __restrict__ wqkv,
    const float* __restrict__ bias, ushort* __restrict__ qk,
    ushort* __restrict__ v) {
  int b = blockIdx.z;
  int m0 = blockIdx.x * 128;  // n-position
  int n0 = blockIdx.y * 128;  // output channel (0..1536)
  GEMM_PROLOGUE();
  const ushort* Xg = xt + ((size_t)b * 1024 + m0) * 512;
  const ushort* Wg = wqkv + (size_t)n0 * 512;
  const bool isv = (n0 >= 1024);
  if (!isv)
    gemm128<512>(Xg, 512, Wg, 512, acc, As, Bs);
  else
    gemm128<512>(Wg, 512, Xg, 512, acc, As, Bs);
  EPILOGUE_IDX();
  const float qscale = 0.044194173824159216f;  // 512^-0.5
  if (!isv) {
#pragma unroll
    for (int i = 0; i < 4; ++i)
#pragma unroll
      for (int j = 0; j < 4; ++j) {
        int gn = n0 + wn + j * 16 + nl;  // o-channel
        float bs = bias[gn];
        float sc = (gn < 512) ? qscale : 1.f;
#pragma unroll
        for (int r = 0; r < 4; ++r) {
          int gm = m0 + wm + i * 16 + ml + r;  // n-position
          qk[((size_t)b * 1024 + gm) * 1024 + gn] = f2b((acc[i][j][r] + bs) * sc);
        }
      }
  } else {
#pragma unroll
    for (int i = 0; i < 4; ++i)
#pragma unroll
      for (int j = 0; j < 4; ++j)
#pragma unroll
        for (int r = 0; r < 4; ++r) {
          int c = n0 + wm + i * 16 + ml + r;  // o-channel (1024..1536)
          int m = m0 + wn + j * 16 + nl;      // n-position (coalesced)
          v[((size_t)b * 512 + (c - 1024)) * 1024 + m] =
              f2b(acc[i][j][r] + bias[c]);
        }
  }
}

// ---------------- S GEMM: S[n][m] = q_t . k_t^T ----------------
__global__ __launch_bounds__(256) void gemm_s_k(const ushort* __restrict__ qk,
                                                ushort* __restrict__ S) {
  int b = blockIdx.z;
  int m0 = blockIdx.x * 128, n0 = blockIdx.y * 128;
  GEMM_PROLOGUE();
  const ushort* Ag = qk + ((size_t)b * 1024 + m0) * 1024;        // q cols 0..512
  const ushort* Bg = qk + ((size_t)b * 1024 + n0) * 1024 + 512;  // k cols 512..1024
  gemm128<512>(Ag, 1024, Bg, 1024, acc, As, Bs);
  EPILOGUE_IDX();
#pragma unroll
  for (int i = 0; i < 4; ++i)
#pragma unroll
    for (int j = 0; j < 4; ++j)
#pragma unroll
      for (int r = 0; r < 4; ++r) {
        int gm = m0 + wm + i * 16 + ml + r, gn = n0 + wn + j * 16 + nl;
        S[((size_t)b * 1024 + gm) * 1024 + gn] = f2b(acc[i][j][r]);
      }
}

// ---------------- rowwise softmax in place (wave per row, bf16) ----------------
__global__ __launch_bounds__(256) void softmax_k(ushort* __restrict__ S) {
  int row = blockIdx.x * 4 + (threadIdx.x >> 6);
  int lane = threadIdx.x & 63;
  ushort* p = S + (size_t)row * 1024 + lane * 16;
  uint4 u0 = *(uint4*)p, u1 = *(uint4*)(p + 8);
  float v[16];
  const ushort* e0 = (const ushort*)&u0;
  const ushort* e1 = (const ushort*)&u1;
#pragma unroll
  for (int j = 0; j < 8; ++j) { v[j] = b2f(e0[j]); v[8 + j] = b2f(e1[j]); }
  float m = v[0];
#pragma unroll
  for (int j = 1; j < 16; ++j) m = fmaxf(m, v[j]);
#pragma unroll
  for (int off = 32; off >= 1; off >>= 1) m = fmaxf(m, __shfl_xor(m, off));
  float s = 0.f;
#pragma unroll
  for (int j = 0; j < 16; ++j) { v[j] = __expf(v[j] - m); s += v[j]; }
#pragma unroll
  for (int off = 32; off >= 1; off >>= 1) s += __shfl_xor(s, off);
  float inv = 1.f / s;
  uint4 r4[2];
  ushort* r = (ushort*)r4;
#pragma unroll
  for (int j = 0; j < 16; ++j) r[j] = f2b(v[j] * inv);
  *(uint4*)p = r4[0];
  *(uint4*)(p + 8) = r4[1];
}

// ---------------- O GEMM: ot[n][c] = P . v^T ----------------
__global__ __launch_bounds__(256) void gemm_o_k(const ushort* __restrict__ S,
                                                const ushort* __restrict__ v,
                                                ushort* __restrict__ ot) {
  int b = blockIdx.z;
  int m0 = blockIdx.x * 128;  // n-position
  int n0 = blockIdx.y * 128;  // channel (0..512)
  GEMM_PROLOGUE();
  const ushort* Ag = S + ((size_t)b * 1024 + m0) * 1024;
  const ushort* Bg = v + ((size_t)b * 512 + n0) * 1024;
  gemm128<1024>(Ag, 1024, Bg, 1024, acc, As, Bs);
  EPILOGUE_IDX();
#pragma unroll
  for (int i = 0; i < 4; ++i)
#pragma unroll
    for (int j = 0; j < 4; ++j)
#pragma unroll
      for (int r = 0; r < 4; ++r) {
        int gm = m0 + wm + i * 16 + ml + r, gn = n0 + wn + j * 16 + nl;
        ot[((size_t)b * 1024 + gm) * 512 + gn] = f2b(acc[i][j][r]);
      }
}

// ---------------- proj GEMM: out[o][n] = (Wp+I) . ot^T + bias (fp32 out) ----
__global__ __launch_bounds__(256) void gemm_proj_k(
    const ushort* __restrict__ pwI, const ushort* __restrict__ ot,
    const float* __restrict__ pb, float* __restrict__ out) {
  int b = blockIdx.z;
  int m0 = blockIdx.x * 128;  // o-channel (0..512)
  int n0 = blockIdx.y * 128;  // n-position
  GEMM_PROLOGUE();
  const ushort* Ag = pwI + (size_t)m0 * 512;
  const ushort* Bg = ot + ((size_t)b * 1024 + n0) * 512;
  gemm128<512>(Ag, 512, Bg, 512, acc, As, Bs);
  EPILOGUE_IDX();
#pragma unroll
  for (int i = 0; i < 4; ++i)
#pragma unroll
    for (int j = 0; j < 4; ++j)
#pragma unroll
      for (int r = 0; r < 4; ++r) {
        int gm = m0 + wm + i * 16 + ml + r;  // o-channel
        int gn = n0 + wn + j * 16 + nl;      // n-position
        out[((size_t)b * 512 + gm) * 1024 + gn] = acc[i][j][r] + pb[gm];
      }
}

extern "C" void kernel_launch(void* const* d_in, const int* in_sizes, int n_in,
                              void* d_out, int out_size, void* d_ws,
                              size_t ws_size, hipStream_t stream) {
  const float* x = (const float*)d_in[0];
  const float* gw = (const float*)d_in[1];
  const float* gb = (const float*)d_in[2];
  const float* wqkv_f = (const float*)d_in[3];
  const float* bqkv = (const float*)d_in[4];
  const float* pw = (const float*)d_in[5];
  const float* pb = (const float*)d_in[6];
  float* out = (float*)d_out;

  // Workspace layout (84.5 MB peak, region reuse):
  //   0        scale (32KB)
  //   32768    shift (32KB)
  //   65536    pwI bf16 (512KB)
  //   589824   wqkv bf16 (1.5MB)  [1536*512*2]
  //   2162688  R1 (32MB): xt[b][n][c] bf16 (first 16MB); later S[b][n][m]
  //   35717120 R2 (32MB): qk[b][n][0..1024) bf16; later ot[b][n][c] (16MB)
  //   69271552 R3 (16MB): v[b][c][m] bf16
  char* ws = (char*)d_ws;
  float* scale = (float*)(ws + 0);
  float* shift = (float*)(ws + 32768);
  ushort* pwI = (ushort*)(ws + 65536);
  ushort* wqkv = (ushort*)(ws + 589824);
  ushort* xt = (ushort*)(ws + 2162688);
  ushort* S = xt;                       // S overwrites dead xt region
  ushort* qk = (ushort*)(ws + 35717120);
  ushort* ot = qk;                      // ot overwrites dead qk region
  ushort* v = (ushort*)(ws + 69271552);

  prep_k<<<dim3(4608), 256, 0, stream>>>(x, gw, gb, scale, shift, pw, pwI,
                                         wqkv_f, wqkv);
  xn_t_k<<<dim3(16, 8, 16), 256, 0, stream>>>(x, scale, shift, xt);
  gemm_qkv_k<<<dim3(8, 12, 16), 256, 0, stream>>>(xt, wqkv, bqkv, qk, v);
  gemm_s_k<<<dim3(8, 8, 16), 256, 0, stream>>>(qk, S);
  softmax_k<<<dim3(4096), 256, 0, stream>>>(S);
  gemm_o_k<<<dim3(8, 4, 16), 256, 0, stream>>>(S, v, ot);
  gemm_proj_k<<<dim3(4, 8, 16), 256, 0, stream>>>(pwI, ot, pb, out);
}